// Round 4
// baseline (147.129 us; speedup 1.0000x reference)
//
#include <hip/hip_runtime.h>
#include <math.h>

#ifndef M_PI
#define M_PI 3.14159265358979323846
#endif

#define NFILT   10
#define THREADS 1024
#define CHUNK   16
#define SEGLEN  (THREADS * CHUNK)   // 16384
#define NSEG    4                   // L = 65536
#define LTOT    (SEGLEN * NSEG)
#define NWAVE   (THREADS / 64)      // 16

__global__ __launch_bounds__(THREADS, 4) void eq_cascade_kernel(
    const float* __restrict__ x,
    const float* __restrict__ w0_in,
    const float* __restrict__ qinv_in,
    const float* __restrict__ gain_in,
    float* __restrict__ out)
{
    __shared__ float  coef[NFILT][5];        // b0,b1,b2,a1,a2 (normalized)
    __shared__ float4 mats4[NFILT][7];       // A^(2^r), r=0..6, 2x2 row-major (A = 16-sample map)
    __shared__ float2 bnd[THREADS];          // raw-x chunk boundary (per segment)
    __shared__ float2 waveP[2][NWAVE];       // per-wave inclusive particular totals (dbuf by filter)
    __shared__ float2 sy[2][NFILT];          // filter-k TRUE output end-state, dbuf by segment
    __shared__ float2 sx[2];                 // raw-x end-state, dbuf by segment

    const int tid  = threadIdx.x;
    const int lane = tid & 63;
    const int wid  = tid >> 6;
    const int b    = blockIdx.x;

    // ---- precompute coefficients + chunk-transfer matrix powers (f64) ----
    if (tid < NFILT) {
        const int k = tid;
        const double w0 = M_PI / (1.0 + exp(-(double)w0_in[b * NFILT + k]));
        const double qi = exp((double)qinv_in[b * NFILT + k]);
        const double A  = exp((double)gain_in[b * NFILT + k]);
        const double cw = cos(w0);
        const double al = sin(w0) * qi * 0.5;
        double B0, B1, B2, A0, A1, A2;
        if (k == 0) {                       // low shelf
            const double Ap1 = A + 1.0, Am1 = A - 1.0, tsa = 2.0 * sqrt(A) * al;
            B0 = A * (Ap1 - Am1 * cw + tsa);
            B1 = 2.0 * A * (Am1 - Ap1 * cw);
            B2 = A * (Ap1 - Am1 * cw - tsa);
            A0 = Ap1 + Am1 * cw + tsa;
            A1 = -2.0 * (Am1 + Ap1 * cw);
            A2 = Ap1 + Am1 * cw - tsa;
        } else if (k == NFILT - 1) {        // high shelf
            const double Ap1 = A + 1.0, Am1 = A - 1.0, tsa = 2.0 * sqrt(A) * al;
            B0 = A * (Ap1 + Am1 * cw + tsa);
            B1 = -2.0 * A * (Am1 + Ap1 * cw);
            B2 = A * (Ap1 + Am1 * cw - tsa);
            A0 = Ap1 - Am1 * cw + tsa;
            A1 = 2.0 * (Am1 - Ap1 * cw);
            A2 = Ap1 - Am1 * cw - tsa;
        } else {                            // peaking
            const double aA = al * A, aiA = al / A;
            B0 = 1.0 + aA;  B1 = -2.0 * cw; B2 = 1.0 - aA;
            A0 = 1.0 + aiA; A1 = B1;        A2 = 1.0 - aiA;
        }
        const double inv = 1.0 / A0;
        const double a1 = A1 * inv, a2 = A2 * inv;
        coef[k][0] = (float)(B0 * inv);
        coef[k][1] = (float)(B1 * inv);
        coef[k][2] = (float)(B2 * inv);
        coef[k][3] = (float)a1;
        coef[k][4] = (float)a2;

        // homogeneous impulse response over one chunk (CHUNK samples)
        double um1 = 1.0, um2 = 0.0, um3 = 0.0;
        for (int t = 0; t < CHUNK; ++t) {
            const double un = -a1 * um1 - a2 * um2;
            um3 = um2; um2 = um1; um1 = un;
        }
        double M0 = um1, M1 = -a2 * um2, M2 = um2, M3 = -a2 * um3;
        for (int r = 0; r < 7; ++r) {
            mats4[k][r] = make_float4((float)M0, (float)M1, (float)M2, (float)M3);
            const double n0 = M0 * M0 + M1 * M2;
            const double n1 = M0 * M1 + M1 * M3;
            const double n2 = M2 * M0 + M3 * M2;
            const double n3 = M2 * M1 + M3 * M3;
            M0 = n0; M1 = n1; M2 = n2; M3 = n3;
        }
        sy[0][k] = make_float2(0.f, 0.f);
    }
    if (tid == 0) sx[0] = make_float2(0.f, 0.f);
    __syncthreads();

    const float* xb = x   + (size_t)b * LTOT;
    float*       ob = out + (size_t)b * LTOT;

    float sig[CHUNK];

    for (int s = 0; s < NSEG; ++s) {
        const int p = s & 1, np = p ^ 1;

        const float4* src = reinterpret_cast<const float4*>(xb + (size_t)s * SEGLEN + (size_t)tid * CHUNK);
        #pragma unroll
        for (int i = 0; i < CHUNK / 4; ++i) {
            const float4 v = src[i];
            sig[4 * i + 0] = v.x; sig[4 * i + 1] = v.y;
            sig[4 * i + 2] = v.z; sig[4 * i + 3] = v.w;
        }

        // raw-x boundary exchange (once per segment)
        bnd[tid] = make_float2(sig[CHUNK - 1], sig[CHUNK - 2]);
        if (tid == THREADS - 1) sx[np] = make_float2(sig[CHUNK - 1], sig[CHUNK - 2]);
        __syncthreads();

        float incA, incB;     // true (prev1, prev2) of current filter's INPUT at chunk start
        {
            const float2 t0 = (tid == 0) ? sx[p] : bnd[tid - 1];
            incA = t0.x; incB = t0.y;
        }
        float a1p = 0.f, a2p = 0.f;   // previous filter's a-coefs (0 => input is raw x)

        for (int k = 0; k < NFILT; ++k) {
            const float b0  = coef[k][0], b1c = coef[k][1], b2 = coef[k][2];
            const float a1  = coef[k][3], a2  = coef[k][4];

            // ---- fused: finalize(k-1) + FIR(k) + zero-init particular(k) ----
            float y1 = incA, y2 = incB;   // rolling true input window
            float z1 = 0.f, z2 = 0.f;     // zero-init particular state
            #pragma unroll
            for (int t = 0; t < CHUNK; ++t) {
                const float yn = sig[t] - a1p * y1 - a2p * y2;  // finalize prev filter
                const float c  = b0 * yn + b1c * y1 + b2 * y2;  // FIR of filter k
                const float z  = c - a1 * z1 - a2 * z2;         // zero-init recurrence
                sig[t] = c;
                y2 = y1; y1 = yn;
                z2 = z1; z1 = z;
            }

            // ---- in-wave affine scan of particular end-states ----
            float Sa = z1, Sb = z2;
            #pragma unroll
            for (int r = 0; r < 6; ++r) {
                const int d = 1 << r;
                const float4 M = mats4[k][r];
                const float ta = __shfl_up(Sa, d, 64);
                const float tb = __shfl_up(Sb, d, 64);
                const float na = Sa + M.x * ta + M.y * tb;
                const float nb = Sb + M.z * ta + M.w * tb;
                if (lane >= d) { Sa = na; Sb = nb; }
            }
            const int buf = k & 1;
            if (lane == 63) waveP[buf][wid] = make_float2(Sa, Sb);
            __syncthreads();

            // ---- cross-wave combine -> true incoming OUTPUT state of filter k ----
            const float2 sv = sy[p][k];
            float Wa = sv.x, Wb = sv.y;
            const float4 M6 = mats4[k][6];
            for (int j = 0; j < wid; ++j) {
                const float2 Pj = waveP[buf][j];
                const float na = M6.x * Wa + M6.y * Wb + Pj.x;
                const float nb = M6.z * Wa + M6.w * Wb + Pj.y;
                Wa = na; Wb = nb;
            }
            if (tid == THREADS - 1) {     // segment-end true state for next segment
                sy[np][k] = make_float2(M6.x * Wa + M6.y * Wb + Sa,
                                        M6.z * Wa + M6.w * Wb + Sb);
            }
            #pragma unroll
            for (int r = 0; r < 6; ++r) {  // apply A^lane
                if ((lane >> r) & 1) {
                    const float4 M = mats4[k][r];
                    const float na = M.x * Wa + M.y * Wb;
                    const float nb = M.z * Wa + M.w * Wb;
                    Wa = na; Wb = nb;
                }
            }
            float Ea = __shfl_up(Sa, 1, 64);
            float Eb = __shfl_up(Sb, 1, 64);
            if (lane == 0) { Ea = 0.f; Eb = 0.f; }

            incA = Wa + Ea;               // true (y_-1, y_-2) of filter k's output
            incB = Wb + Eb;
            a1p = a1; a2p = a2;
        }

        // ---- tail: finalize filter 9 + vectorized store ----
        {
            float y1 = incA, y2 = incB;
            float4* dst = reinterpret_cast<float4*>(ob + (size_t)s * SEGLEN + (size_t)tid * CHUNK);
            #pragma unroll
            for (int i = 0; i < CHUNK / 4; ++i) {
                float4 o;
                o.x = sig[4 * i + 0] - a1p * y1 - a2p * y2; y2 = y1; y1 = o.x;
                o.y = sig[4 * i + 1] - a1p * y1 - a2p * y2; y2 = y1; y1 = o.y;
                o.z = sig[4 * i + 2] - a1p * y1 - a2p * y2; y2 = y1; y1 = o.z;
                o.w = sig[4 * i + 3] - a1p * y1 - a2p * y2; y2 = y1; y1 = o.w;
                dst[i] = o;
            }
        }
    }
}

extern "C" void kernel_launch(void* const* d_in, const int* in_sizes, int n_in,
                              void* d_out, int out_size, void* d_ws, size_t ws_size,
                              hipStream_t stream) {
    const float* x    = (const float*)d_in[0];
    const float* w0   = (const float*)d_in[1];
    const float* qinv = (const float*)d_in[2];
    const float* gain = (const float*)d_in[3];
    float* out = (float*)d_out;

    const int B = in_sizes[1] / NFILT;   // 256 batches (C=1 folded in)
    eq_cascade_kernel<<<B, THREADS, 0, stream>>>(x, w0, qinv, gain, out);
}

// Round 5
// 115.962 us; speedup vs baseline: 1.2688x; 1.2688x over previous
//
#include <hip/hip_runtime.h>
#include <math.h>

#ifndef M_PI
#define M_PI 3.14159265358979323846
#endif

#define NFILT   10
#define THREADS 1024
#define CHUNK   32
#define SEGLEN  (THREADS * CHUNK)   // 32768
#define NSEG    2                   // L = 65536
#define LTOT    (SEGLEN * NSEG)
#define NWAVE   (THREADS / 64)      // 16

// waves_per_eu(4,4): a 1024-thread block is 4 waves/SIMD (1 block/CU), so
// occupancy >4 waves/EU is impossible anyway. Setting max=4 makes the
// register allocator target the 128-VGPR budget instead of minimizing
// VGPRs for 8+ waves/EU (which spilled sig[] in R1-R4: VGPR_Count 32-56).
__global__ void
__attribute__((amdgpu_flat_work_group_size(THREADS, THREADS)))
__attribute__((amdgpu_waves_per_eu(4, 4)))
eq_cascade_kernel(
    const float* __restrict__ x,
    const float* __restrict__ w0_in,
    const float* __restrict__ qinv_in,
    const float* __restrict__ gain_in,
    float* __restrict__ out)
{
    __shared__ float  coef[NFILT][5];        // b0,b1,b2,a1,a2 (normalized)
    __shared__ float4 mats4[NFILT][7];       // A^(2^r), r=0..6, 2x2 row-major
    __shared__ float2 bnd[THREADS];          // raw-x chunk boundary (per segment)
    __shared__ float2 waveP[2][NWAVE];       // per-wave inclusive particular totals (dbuf by filter)
    __shared__ float2 sy[2][NFILT];          // filter-k TRUE output end-state, dbuf by segment
    __shared__ float2 sx[2];                 // raw-x end-state, dbuf by segment

    const int tid  = threadIdx.x;
    const int lane = tid & 63;
    const int wid  = tid >> 6;
    const int b    = blockIdx.x;

    // ---- precompute coefficients + chunk-transfer matrix powers (f64) ----
    if (tid < NFILT) {
        const int k = tid;
        const double w0 = M_PI / (1.0 + exp(-(double)w0_in[b * NFILT + k]));
        const double qi = exp((double)qinv_in[b * NFILT + k]);
        const double A  = exp((double)gain_in[b * NFILT + k]);
        const double cw = cos(w0);
        const double al = sin(w0) * qi * 0.5;
        double B0, B1, B2, A0, A1, A2;
        if (k == 0) {                       // low shelf
            const double Ap1 = A + 1.0, Am1 = A - 1.0, tsa = 2.0 * sqrt(A) * al;
            B0 = A * (Ap1 - Am1 * cw + tsa);
            B1 = 2.0 * A * (Am1 - Ap1 * cw);
            B2 = A * (Ap1 - Am1 * cw - tsa);
            A0 = Ap1 + Am1 * cw + tsa;
            A1 = -2.0 * (Am1 + Ap1 * cw);
            A2 = Ap1 + Am1 * cw - tsa;
        } else if (k == NFILT - 1) {        // high shelf
            const double Ap1 = A + 1.0, Am1 = A - 1.0, tsa = 2.0 * sqrt(A) * al;
            B0 = A * (Ap1 + Am1 * cw + tsa);
            B1 = -2.0 * A * (Am1 + Ap1 * cw);
            B2 = A * (Ap1 + Am1 * cw - tsa);
            A0 = Ap1 - Am1 * cw + tsa;
            A1 = 2.0 * (Am1 - Ap1 * cw);
            A2 = Ap1 - Am1 * cw - tsa;
        } else {                            // peaking
            const double aA = al * A, aiA = al / A;
            B0 = 1.0 + aA;  B1 = -2.0 * cw; B2 = 1.0 - aA;
            A0 = 1.0 + aiA; A1 = B1;        A2 = 1.0 - aiA;
        }
        const double inv = 1.0 / A0;
        const double a1 = A1 * inv, a2 = A2 * inv;
        coef[k][0] = (float)(B0 * inv);
        coef[k][1] = (float)(B1 * inv);
        coef[k][2] = (float)(B2 * inv);
        coef[k][3] = (float)a1;
        coef[k][4] = (float)a2;

        // homogeneous impulse response over one chunk
        double um1 = 1.0, um2 = 0.0, um3 = 0.0;
        for (int t = 0; t < CHUNK; ++t) {
            const double un = -a1 * um1 - a2 * um2;
            um3 = um2; um2 = um1; um1 = un;
        }
        double M0 = um1, M1 = -a2 * um2, M2 = um2, M3 = -a2 * um3;
        for (int r = 0; r < 7; ++r) {
            mats4[k][r] = make_float4((float)M0, (float)M1, (float)M2, (float)M3);
            const double n0 = M0 * M0 + M1 * M2;
            const double n1 = M0 * M1 + M1 * M3;
            const double n2 = M2 * M0 + M3 * M2;
            const double n3 = M2 * M1 + M3 * M3;
            M0 = n0; M1 = n1; M2 = n2; M3 = n3;
        }
        sy[0][k] = make_float2(0.f, 0.f);
    }
    if (tid == 0) sx[0] = make_float2(0.f, 0.f);
    __syncthreads();

    const float* xb = x   + (size_t)b * LTOT;
    float*       ob = out + (size_t)b * LTOT;

    float sig[CHUNK];

    for (int s = 0; s < NSEG; ++s) {
        const int p = s & 1, np = p ^ 1;

        const float4* src = reinterpret_cast<const float4*>(xb + (size_t)s * SEGLEN + (size_t)tid * CHUNK);
        #pragma unroll
        for (int i = 0; i < CHUNK / 4; ++i) {
            const float4 v = src[i];
            sig[4 * i + 0] = v.x; sig[4 * i + 1] = v.y;
            sig[4 * i + 2] = v.z; sig[4 * i + 3] = v.w;
        }

        // raw-x boundary exchange (once per segment)
        bnd[tid] = make_float2(sig[CHUNK - 1], sig[CHUNK - 2]);
        if (tid == THREADS - 1) sx[np] = make_float2(sig[CHUNK - 1], sig[CHUNK - 2]);
        __syncthreads();

        float incA, incB;     // true (prev1, prev2) of current filter's INPUT at chunk start
        {
            const float2 t0 = (tid == 0) ? sx[p] : bnd[tid - 1];
            incA = t0.x; incB = t0.y;
        }
        float a1p = 0.f, a2p = 0.f;   // previous filter's a-coefs (0 => input is raw x)

        for (int k = 0; k < NFILT; ++k) {
            const float b0  = coef[k][0], b1c = coef[k][1], b2 = coef[k][2];
            const float a1  = coef[k][3], a2  = coef[k][4];

            // ---- fused: finalize(k-1) + FIR(k) + zero-init particular(k) ----
            float y1 = incA, y2 = incB;   // rolling true input window
            float z1 = 0.f, z2 = 0.f;     // zero-init particular state
            #pragma unroll
            for (int t = 0; t < CHUNK; ++t) {
                const float yn = sig[t] - a1p * y1 - a2p * y2;  // finalize prev filter
                const float c  = b0 * yn + b1c * y1 + b2 * y2;  // FIR of filter k
                const float z  = c - a1 * z1 - a2 * z2;         // zero-init recurrence
                sig[t] = c;
                y2 = y1; y1 = yn;
                z2 = z1; z1 = z;
            }

            // ---- in-wave affine scan of particular end-states ----
            float Sa = z1, Sb = z2;
            #pragma unroll
            for (int r = 0; r < 6; ++r) {
                const int d = 1 << r;
                const float4 M = mats4[k][r];
                float ta = __shfl_up(Sa, d, 64);
                float tb = __shfl_up(Sb, d, 64);
                const bool act = (lane >= d);
                ta = act ? ta : 0.f;      // cndmask, no exec-mask branch
                tb = act ? tb : 0.f;
                Sa = Sa + M.x * ta + M.y * tb;
                Sb = Sb + M.z * ta + M.w * tb;
            }
            const int buf = k & 1;
            if (lane == 63) waveP[buf][wid] = make_float2(Sa, Sb);
            __syncthreads();

            // ---- cross-wave combine -> true incoming OUTPUT state of filter k ----
            const float2 sv = sy[p][k];
            float Wa = sv.x, Wb = sv.y;
            const float4 M6 = mats4[k][6];
            for (int j = 0; j < wid; ++j) {
                const float2 Pj = waveP[buf][j];
                const float na = M6.x * Wa + M6.y * Wb + Pj.x;
                const float nb = M6.z * Wa + M6.w * Wb + Pj.y;
                Wa = na; Wb = nb;
            }
            if (tid == THREADS - 1) {     // segment-end true state for next segment
                sy[np][k] = make_float2(M6.x * Wa + M6.y * Wb + Sa,
                                        M6.z * Wa + M6.w * Wb + Sb);
            }
            #pragma unroll
            for (int r = 0; r < 6; ++r) {  // apply A^lane (powers commute)
                const float4 M = mats4[k][r];
                const bool bit = (lane >> r) & 1;
                const float na = M.x * Wa + M.y * Wb;
                const float nb = M.z * Wa + M.w * Wb;
                Wa = bit ? na : Wa;
                Wb = bit ? nb : Wb;
            }
            float Ea = __shfl_up(Sa, 1, 64);
            float Eb = __shfl_up(Sb, 1, 64);
            if (lane == 0) { Ea = 0.f; Eb = 0.f; }

            incA = Wa + Ea;               // true (y_-1, y_-2) of filter k's output
            incB = Wb + Eb;
            a1p = a1; a2p = a2;
        }

        // ---- tail: finalize filter 9 + vectorized store ----
        {
            float y1 = incA, y2 = incB;
            float4* dst = reinterpret_cast<float4*>(ob + (size_t)s * SEGLEN + (size_t)tid * CHUNK);
            #pragma unroll
            for (int i = 0; i < CHUNK / 4; ++i) {
                float4 o;
                o.x = sig[4 * i + 0] - a1p * y1 - a2p * y2; y2 = y1; y1 = o.x;
                o.y = sig[4 * i + 1] - a1p * y1 - a2p * y2; y2 = y1; y1 = o.y;
                o.z = sig[4 * i + 2] - a1p * y1 - a2p * y2; y2 = y1; y1 = o.z;
                o.w = sig[4 * i + 3] - a1p * y1 - a2p * y2; y2 = y1; y1 = o.w;
                dst[i] = o;
            }
        }
    }
}

extern "C" void kernel_launch(void* const* d_in, const int* in_sizes, int n_in,
                              void* d_out, int out_size, void* d_ws, size_t ws_size,
                              hipStream_t stream) {
    const float* x    = (const float*)d_in[0];
    const float* w0   = (const float*)d_in[1];
    const float* qinv = (const float*)d_in[2];
    const float* gain = (const float*)d_in[3];
    float* out = (float*)d_out;

    const int B = in_sizes[1] / NFILT;   // 256 batches (C=1 folded in)
    eq_cascade_kernel<<<B, THREADS, 0, stream>>>(x, w0, qinv, gain, out);
}